// Round 6
// baseline (13.089 us; speedup 1.0000x reference)
//
#include <hip/hip_runtime.h>
#include <type_traits>

typedef float v2f __attribute__((ext_vector_type(2)));

constexpr int BLOCK = 256;          // 4 waves; wave w owns lags {2w, 2w+1}
constexpr int SPB = 256;            // samples per block (4 per lane, two pairs)
constexpr int HALO_LO = 10;         // l_max(7) + m_max(3)
constexpr int HALO_HI = 3;          // +m_max for the c (leading) term
constexpr int SIG = SPB + HALO_LO + HALO_HI;   // 269
constexpr int PSTRIDE = 128;        // distance between a lane's two sample pairs

// ---------------- compile-time unroll helper ----------------
template<int I, int N, typename F>
__device__ __forceinline__ void unroll_for(F&& f) {
    if constexpr (I < N) {
        f(std::integral_constant<int, I>{});
        unroll_for<I + 1, N>(static_cast<F&&>(f));
    }
}

// ---------------- single fused kernel ----------------
// y[n] = sum_L x[n-L] * sum_s P_{L,s}(r[n-L+d(s)]),  d: 0,-1,-2,-3,+1,+2,+3
// Wave w: lags {2w, 2w+1}. Lane: samples {2*s2, 2*s2+1} and {+128, +129}
// (two PAIRS) -- 4 samples amortize each coefficient broadcast, while the
// 8 B lane stride keeps every window ds_read at 2-way bank aliasing (free),
// unlike 4-contiguous-samples (16 B stride = 8-way conflict, R5).
// Signal staged as split re/im/abs float arrays (b32 reads, conflict-free).
// wlds[(l*7+s)*16 + 2k + {0,1}] = (re,im) of W[l][s][k].
// slot 0 = a[:,l] + b[:,l,0] + c[:,l,0]; slots 1..3 = b m=1..3; 4..6 = c m=1..3.
__global__ __launch_bounds__(BLOCK) void gmp_kernel(
    const float* __restrict__ x,
    const float* __restrict__ a_re, const float* __restrict__ a_im,
    const float* __restrict__ b_re, const float* __restrict__ b_im,
    const float* __restrict__ c_re, const float* __restrict__ c_im,
    float* __restrict__ out, int N)
{
    __shared__ float sxr[SIG], sxi[SIG], sab[SIG];
    __shared__ __align__(16) float2 part[4][SPB];   // [wave][sample]
    __shared__ __align__(16) float wlds[896];       // folded coefficients

    const int t = threadIdx.x;
    const int n0 = blockIdx.x * SPB;

    // ---- stage signal + envelope with clipped halo ----
    const float2* x2 = (const float2*)x;
    for (int j = t; j < SIG; j += BLOCK) {
        int g = n0 - HALO_LO + j;
        g = max(0, min(N - 1, g));
        float2 v = x2[g];
        sxr[j] = v.x;
        sxi[j] = v.y;
        sab[j] = __builtin_amdgcn_sqrtf(fmaf(v.x, v.x, v.y * v.y));
    }

    // ---- fold coefficients into LDS (overlaps halo staging) ----
    for (int idx = t; idx < 448; idx += BLOCK) {
        int l = idx / 56;
        int rem = idx - l * 56;
        int s = rem >> 3;
        int k = rem & 7;
        int akl = k * 8 + l;               // a[k][l]; b/c[k][l][m] = akl*4 + m
        float re, im;
        if (s == 0) {
            re = a_re[akl] + b_re[akl * 4] + c_re[akl * 4];
            im = a_im[akl] + b_im[akl * 4] + c_im[akl * 4];
        } else if (s <= 3) {
            re = b_re[akl * 4 + s];
            im = b_im[akl * 4 + s];
        } else {
            re = c_re[akl * 4 + (s - 3)];
            im = c_im[akl * 4 + (s - 3)];
        }
        wlds[idx * 2]     = re;
        wlds[idx * 2 + 1] = im;
    }
    __syncthreads();

    const int s2 = t & 63;                                   // sample lane
    const int wv = __builtin_amdgcn_readfirstlane(t >> 6);   // wave id 0..3
    const float* cw = &wlds[wv * 224];     // this wave's 14 slots (uniform base)

    // pair bases: pair P covers block-local samples {2*s2+128P, +1}
    // slot (ll,d,P,q) reads sab[rbP + q - ll + d + 4] (index in [0,8])
    const int rb0 = 2 * s2 + 6 - 2 * wv;
    const int rb1 = rb0 + PSTRIDE;
    float rvA[9], rvB[9];
    unroll_for<0, 9>([&](auto I) {
        rvA[I.value] = sab[rb0 + I.value];
        rvB[I.value] = sab[rb1 + I.value];
    });
    // x windows: lag ll, sample q uses xv?[q - ll + 1] (index in [0,2])
    float xArr[3], xAri[3], xBrr[3], xBri[3];
    unroll_for<0, 3>([&](auto I) {
        xArr[I.value] = sxr[rb0 + 3 + I.value];
        xAri[I.value] = sxi[rb0 + 3 + I.value];
        xBrr[I.value] = sxr[rb1 + 3 + I.value];
        xBri[I.value] = sxi[rb1 + 3 + I.value];
    });

    float yr[4] = {0.f, 0.f, 0.f, 0.f};    // [2P+q]
    float yi[4] = {0.f, 0.f, 0.f, 0.f};

    unroll_for<0, 2>([&](auto LL) {
        constexpr int ll = LL.value;       // local lag: L = 2*wv + ll
        v2f S[4] = {{0.f,0.f},{0.f,0.f},{0.f,0.f},{0.f,0.f}};
        unroll_for<0, 7>([&](auto Sc) {
            constexpr int s = Sc.value;
            constexpr int d = (s == 0) ? 0 : ((s <= 3) ? -s : (s - 3));
            constexpr int off = ll * 112 + s * 16;
            // wave-uniform coefficient fetch from LDS (broadcast ds_read)
            v2f wk[8];
            unroll_for<0, 8>([&](auto K) {
                wk[K.value] = *(const v2f*)&cw[off + 2 * K.value];
            });
            // r values for the 4 samples of this slot
            const float r0A = rvA[0 - ll + d + 4];
            const float r1A = rvA[1 - ll + d + 4];
            const float r0B = rvB[0 - ll + d + 4];
            const float r1B = rvB[1 - ll + d + 4];
            v2f acc[4];
            unroll_for<0, 4>([&](auto Q) { acc[Q.value] = wk[7]; });
            unroll_for<0, 7>([&](auto Kc) {
                constexpr int k = 6 - Kc.value;
                acc[0] = __builtin_elementwise_fma(acc[0], (v2f){r0A, r0A}, wk[k]);
                acc[1] = __builtin_elementwise_fma(acc[1], (v2f){r1A, r1A}, wk[k]);
                acc[2] = __builtin_elementwise_fma(acc[2], (v2f){r0B, r0B}, wk[k]);
                acc[3] = __builtin_elementwise_fma(acc[3], (v2f){r1B, r1B}, wk[k]);
            });
            unroll_for<0, 4>([&](auto Q) { S[Q.value] += acc[Q.value]; });
        });
        // combine with x[n - L] per sample
        unroll_for<0, 2>([&](auto Q) {     // q within pair
            constexpr int q = Q.value;
            {   // pair A
                const float xre = xArr[q - ll + 1], xim = xAri[q - ll + 1];
                yr[q] = fmaf(xre, S[q].x, fmaf(-xim, S[q].y, yr[q]));
                yi[q] = fmaf(xre, S[q].y, fmaf( xim, S[q].x, yi[q]));
            }
            {   // pair B
                const float xre = xBrr[q - ll + 1], xim = xBri[q - ll + 1];
                yr[2 + q] = fmaf(xre, S[2 + q].x, fmaf(-xim, S[2 + q].y, yr[2 + q]));
                yi[2 + q] = fmaf(xre, S[2 + q].y, fmaf( xim, S[2 + q].x, yi[2 + q]));
            }
        });
    });

    // partial writes: one dense float4 (b128) per pair -- conflict-free
    {
        float4 pa = make_float4(yr[0], yi[0], yr[1], yi[1]);
        float4 pb = make_float4(yr[2], yi[2], yr[3], yi[3]);
        *(float4*)&part[wv][2 * s2]           = pa;
        *(float4*)&part[wv][2 * s2 + PSTRIDE] = pb;
    }
    __syncthreads();

    // all 256 lanes reduce one sample each (dense b64 reads per wave row)
    {
        float2 p0 = part[0][t];
        float2 p1 = part[1][t];
        float2 p2 = part[2][t];
        float2 p3 = part[3][t];
        float2 r;
        r.x = (p0.x + p1.x) + (p2.x + p3.x);
        r.y = (p0.y + p1.y) + (p2.y + p3.y);
        const int n = n0 + t;
        if (n < N) ((float2*)out)[n] = r;
    }
}

extern "C" void kernel_launch(void* const* d_in, const int* in_sizes, int n_in,
                              void* d_out, int out_size, void* d_ws, size_t ws_size,
                              hipStream_t stream) {
    const float* x    = (const float*)d_in[0];
    const float* a_re = (const float*)d_in[1];
    const float* a_im = (const float*)d_in[2];
    const float* b_re = (const float*)d_in[3];
    const float* b_im = (const float*)d_in[4];
    const float* c_re = (const float*)d_in[5];
    const float* c_im = (const float*)d_in[6];
    float* out = (float*)d_out;

    int N = in_sizes[0] / 2;
    int grid = (N + SPB - 1) / SPB;        // 1024 blocks
    gmp_kernel<<<grid, BLOCK, 0, stream>>>(x, a_re, a_im, b_re, b_im,
                                           c_re, c_im, out, N);
}

// Round 7
// 12.801 us; speedup vs baseline: 1.0225x; 1.0225x over previous
//
#include <hip/hip_runtime.h>
#include <type_traits>

typedef float v2f __attribute__((ext_vector_type(2)));

constexpr int BLOCK = 512;          // 8 waves; wave w owns lag w
constexpr int CHUNKS = 4;           // chunks per block (coeff reuse x4)
constexpr int SPB = 256;            // samples per chunk
constexpr int SPBLK = SPB * CHUNKS; // 1024 samples per block
constexpr int HALO_LO = 10;         // l_max(7) + m_max(3)
constexpr int HALO_HI = 3;          // +m_max for the c (leading) term
constexpr int SIG = SPB + HALO_LO + HALO_HI;   // 269
constexpr int PSTRIDE = 128;        // distance between a lane's two sample pairs

// ---------------- compile-time unroll helper ----------------
template<int I, int N, typename F>
__device__ __forceinline__ void unroll_for(F&& f) {
    if constexpr (I < N) {
        f(std::integral_constant<int, I>{});
        unroll_for<I + 1, N>(static_cast<F&&>(f));
    }
}

// ---------------- single fused persistent-chunk kernel ----------------
// y[n] = sum_L x[n-L] * sum_s P_{L,s}(r[n-L+d(s)]),  d: 0,-1,-2,-3,+1,+2,+3
// 8 waves/block, wave w owns lag w ALONE. Each wave loads its 56 complex
// coefficients (wk[7][8], 112 VGPRs) from LDS ONCE, then processes 4 chunks
// of 256 samples -- cutting the DS-pipe coefficient-broadcast traffic 4x
// (the modeled bottleneck: ~5us/CU of ds_read instruction cycles).
// Lane owns samples {2*s2, 2*s2+1} and {+128, +129} per chunk (8 B lane
// stride -> 2-way bank aliasing, free).
// wlds[(l*7+s)*16 + 2k + {0,1}] = (re,im) of W[l][s][k].
// slot 0 = a[:,l] + b[:,l,0] + c[:,l,0]; slots 1..3 = b m=1..3; 4..6 = c m=1..3.
__global__ __launch_bounds__(BLOCK, 2) void gmp_kernel(
    const float* __restrict__ x,
    const float* __restrict__ a_re, const float* __restrict__ a_im,
    const float* __restrict__ b_re, const float* __restrict__ b_im,
    const float* __restrict__ c_re, const float* __restrict__ c_im,
    float* __restrict__ out, int N)
{
    __shared__ float sxr[SIG], sxi[SIG], sab[SIG];
    __shared__ __align__(16) float2 part[8][SPB];   // [wave/lag][sample]
    __shared__ __align__(16) float wlds[896];       // folded coefficients

    const int t = threadIdx.x;
    const int blk0 = blockIdx.x * SPBLK;
    const float2* x2 = (const float2*)x;

    // ---- stage chunk 0 signal + envelope with clipped halo ----
    if (t < SIG) {
        int g = blk0 - HALO_LO + t;
        g = max(0, min(N - 1, g));
        float2 v = x2[g];
        sxr[t] = v.x;
        sxi[t] = v.y;
        sab[t] = __builtin_amdgcn_sqrtf(fmaf(v.x, v.x, v.y * v.y));
    }

    // ---- fold coefficients into LDS (overlaps chunk-0 staging) ----
    if (t < 448) {
        int idx = t;
        int l = idx / 56;
        int rem = idx - l * 56;
        int s = rem >> 3;
        int k = rem & 7;
        int akl = k * 8 + l;               // a[k][l]; b/c[k][l][m] = akl*4 + m
        float re, im;
        if (s == 0) {
            re = a_re[akl] + b_re[akl * 4] + c_re[akl * 4];
            im = a_im[akl] + b_im[akl * 4] + c_im[akl * 4];
        } else if (s <= 3) {
            re = b_re[akl * 4 + s];
            im = b_im[akl * 4 + s];
        } else {
            re = c_re[akl * 4 + (s - 3)];
            im = c_im[akl * 4 + (s - 3)];
        }
        wlds[idx * 2]     = re;
        wlds[idx * 2 + 1] = im;
    }
    __syncthreads();

    const int s2 = t & 63;                                   // sample lane
    const int wv = __builtin_amdgcn_readfirstlane(t >> 6);   // wave id = lag, 0..7
    const float* cw = &wlds[wv * 112];     // this wave's 7 slots (uniform base)

    // ---- hoist this wave's coefficients into VGPRs (once per block) ----
    v2f wk[7][8];
    unroll_for<0, 7>([&](auto Sc) {
        unroll_for<0, 8>([&](auto K) {
            wk[Sc.value][K.value] =
                *(const v2f*)&cw[Sc.value * 16 + 2 * K.value];
        });
    });

    // window bases (8 B lane stride -> conflict-free):
    // sample j = 2*s2 + q + 128*P needs sab[j - wv + d + HALO_LO]
    //   = sab[rbP + q + (d+3)], rbP = 2*s2 + 128*P + 7 - wv, idx in [0,7]
    // and x at sx[rbP + 3 + q].
    const int rb0 = 2 * s2 + 7 - wv;
    const int rb1 = rb0 + PSTRIDE;

    for (int c = 0; c < CHUNKS; ++c) {
        const int n0 = blk0 + c * SPB;

        if (c > 0) {
            // restage this chunk's window (prev chunk's readers are done:
            // window reads complete before the pre-epilogue barrier)
            if (t < SIG) {
                int g = n0 - HALO_LO + t;
                g = max(0, min(N - 1, g));
                float2 v = x2[g];
                sxr[t] = v.x;
                sxi[t] = v.y;
                sab[t] = __builtin_amdgcn_sqrtf(fmaf(v.x, v.x, v.y * v.y));
            }
            __syncthreads();   // stage done AND prev epilogue part-reads done
        }

        // ---- per-lane windows ----
        float rvA[8], rvB[8];
        unroll_for<0, 8>([&](auto I) {
            rvA[I.value] = sab[rb0 + I.value];
            rvB[I.value] = sab[rb1 + I.value];
        });
        float xArr[2], xAri[2], xBrr[2], xBri[2];
        unroll_for<0, 2>([&](auto Q) {
            xArr[Q.value] = sxr[rb0 + 3 + Q.value];
            xAri[Q.value] = sxi[rb0 + 3 + Q.value];
            xBrr[Q.value] = sxr[rb1 + 3 + Q.value];
            xBri[Q.value] = sxi[rb1 + 3 + Q.value];
        });

        // ---- 7 slots, 4 independent Horner chains each, coeffs in VGPR ----
        v2f S[4] = {{0.f,0.f},{0.f,0.f},{0.f,0.f},{0.f,0.f}};  // [A0,A1,B0,B1]
        unroll_for<0, 7>([&](auto Sc) {
            constexpr int s = Sc.value;
            constexpr int d3 = (s == 0) ? 3 : ((s <= 3) ? (3 - s) : s);
            const float r0A = rvA[0 + d3];
            const float r1A = rvA[1 + d3];
            const float r0B = rvB[0 + d3];
            const float r1B = rvB[1 + d3];
            v2f acc0 = wk[s][7], acc1 = acc0, acc2 = acc0, acc3 = acc0;
            unroll_for<0, 7>([&](auto Kc) {
                constexpr int k = 6 - Kc.value;
                acc0 = __builtin_elementwise_fma(acc0, (v2f){r0A, r0A}, wk[s][k]);
                acc1 = __builtin_elementwise_fma(acc1, (v2f){r1A, r1A}, wk[s][k]);
                acc2 = __builtin_elementwise_fma(acc2, (v2f){r0B, r0B}, wk[s][k]);
                acc3 = __builtin_elementwise_fma(acc3, (v2f){r1B, r1B}, wk[s][k]);
            });
            S[0] += acc0;
            S[1] += acc1;
            S[2] += acc2;
            S[3] += acc3;
        });

        // ---- multiply by x[n - L] and write partials (b128, dense) ----
        {
            float pr0 = xArr[0]*S[0].x - xAri[0]*S[0].y;
            float pi0 = xArr[0]*S[0].y + xAri[0]*S[0].x;
            float pr1 = xArr[1]*S[1].x - xAri[1]*S[1].y;
            float pi1 = xArr[1]*S[1].y + xAri[1]*S[1].x;
            *(float4*)&part[wv][2 * s2] = make_float4(pr0, pi0, pr1, pi1);
            float qr0 = xBrr[0]*S[2].x - xBri[0]*S[2].y;
            float qi0 = xBrr[0]*S[2].y + xBri[0]*S[2].x;
            float qr1 = xBrr[1]*S[3].x - xBri[1]*S[3].y;
            float qi1 = xBrr[1]*S[3].y + xBri[1]*S[3].x;
            *(float4*)&part[wv][2 * s2 + PSTRIDE] = make_float4(qr0, qi0, qr1, qi1);
        }
        __syncthreads();

        // ---- 8-way reduce: waves 0..3 (t<256) each sum one sample ----
        if (t < SPB) {
            float2 p0 = part[0][t], p1 = part[1][t];
            float2 p2 = part[2][t], p3 = part[3][t];
            float2 p4 = part[4][t], p5 = part[5][t];
            float2 p6 = part[6][t], p7 = part[7][t];
            float2 r;
            r.x = ((p0.x + p1.x) + (p2.x + p3.x)) + ((p4.x + p5.x) + (p6.x + p7.x));
            r.y = ((p0.y + p1.y) + (p2.y + p3.y)) + ((p4.y + p5.y) + (p6.y + p7.y));
            const int n = n0 + t;
            if (n < N) ((float2*)out)[n] = r;
        }
    }
}

extern "C" void kernel_launch(void* const* d_in, const int* in_sizes, int n_in,
                              void* d_out, int out_size, void* d_ws, size_t ws_size,
                              hipStream_t stream) {
    const float* x    = (const float*)d_in[0];
    const float* a_re = (const float*)d_in[1];
    const float* a_im = (const float*)d_in[2];
    const float* b_re = (const float*)d_in[3];
    const float* b_im = (const float*)d_in[4];
    const float* c_re = (const float*)d_in[5];
    const float* c_im = (const float*)d_in[6];
    float* out = (float*)d_out;

    int N = in_sizes[0] / 2;
    int grid = (N + SPBLK - 1) / SPBLK;    // 256 blocks (1 per CU)
    gmp_kernel<<<grid, BLOCK, 0, stream>>>(x, a_re, a_im, b_re, b_im,
                                           c_re, c_im, out, N);
}